// Round 6
// baseline (186.179 us; speedup 1.0000x reference)
//
#include <hip/hip_runtime.h>
#include <hip/hip_bf16.h>
#include <cstdint>
#include <cstddef>

// B=2, N=2048, C=1024, HEADS=16, DIM_HEAD=64
static constexpr int BATCH = 2;
static constexpr int SEQ   = 2048;
static constexpr int CDIM  = 1024;
static constexpr int ROWS  = BATCH * SEQ;   // 4096
static constexpr int QKVN  = 3 * CDIM;      // 3072
static constexpr int QKN   = 2 * CDIM;      // 2048 (Q,K only)

typedef short bf16x8 __attribute__((ext_vector_type(8)));
typedef short bf16x4 __attribute__((ext_vector_type(4)));
typedef float f32x4  __attribute__((ext_vector_type(4)));

__device__ inline short f2bf(float f) {
    union { float f; unsigned u; } v; v.f = f;
    unsigned u = v.u;
    u += 0x7fffu + ((u >> 16) & 1u);
    return (short)(u >> 16);
}

// pack two f32 -> two bf16 (RNE) in one dword; a -> low16, b -> high16
__device__ inline unsigned pk_bf16(float a, float b) {
#if __has_builtin(__builtin_amdgcn_cvt_pk_bf16_f32)
    auto r = __builtin_amdgcn_cvt_pk_bf16_f32(a, b);   // v_cvt_pk_bf16_f32 (gfx950)
    return __builtin_bit_cast(unsigned, r);
#else
    union { float f; unsigned u; } ua, ub;
    ua.f = a; ub.f = b;
    unsigned xa = ua.u + 0x7fffu + ((ua.u >> 16) & 1u);
    unsigned xb = ub.u + 0x7fffu + ((ub.u >> 16) & 1u);
    return __builtin_amdgcn_perm(xb, xa, 0x07060302);
#endif
}

// async global->LDS, 16B/lane; LDS dest = wave-uniform base + lane*16 (m104)
__device__ inline void glds16(const short* g, short* l) {
    __builtin_amdgcn_global_load_lds(
        (const __attribute__((address_space(1))) void*)g,
        (__attribute__((address_space(3))) void*)l, 16, 0, 0);
}

__device__ inline f32x4 mfma16_bf16(bf16x4 a, bf16x4 b, f32x4 c) {
#if __has_builtin(__builtin_amdgcn_mfma_f32_16x16x16bf16_1k)
    return __builtin_amdgcn_mfma_f32_16x16x16bf16_1k(a, b, c, 0, 0, 0);
#else
    asm("v_mfma_f32_16x16x16_bf16 %0, %1, %2, %0" : "+v"(c) : "v"(a), "v"(b));
    return c;
#endif
}

__device__ inline f32x4 mfma32k_bf16(bf16x8 a, bf16x8 b, f32x4 c) {
    return __builtin_amdgcn_mfma_f32_16x16x32_bf16(a, b, c, 0, 0, 0);
}

// ---- LDS chunk swizzle (T2, both-sides per rule 21) ------------------------
// Panels are 16-row x 32-short (64B rows), staged by glds16 with linear LDS
// dest (lane*16B). Un-swizzled, all 16 lanes of a quad-group read the SAME
// 16B column slot of rows 64B apart -> 8-way bank conflict. Fix: XOR the
// chunk index with (row>>1)&3 on BOTH the global source (staging) and the
// LDS read slot. (R1-verified: attn SQ_LDS_BANK_CONFLICT 6.45M -> 164K.)
__device__ inline int swz_src(int lane) {            // staging: global chunk, in shorts
    return ((lane & 3) ^ ((lane >> 3) & 3)) * 8;     // (row_local>>1)&3 == (lane>>3)&3
}
__device__ inline int swz_rd(int quad, int l15) {    // read slot, in shorts
    return (quad ^ ((l15 >> 1) & 3)) * 8;            // (panel_row>>1)&3 == (l15>>1)&3
}

// ---------------------------------------------------------------- fused prep
__global__ __launch_bounds__(256) void prep(const float* __restrict__ x,
                                            const float* __restrict__ wqkv,
                                            const float* __restrict__ wproj,
                                            short* __restrict__ x_bf,
                                            short* __restrict__ wqkvT,
                                            short* __restrict__ wprojT,
                                            float smul) {
    __shared__ float tile[32][33];
    const int bid = blockIdx.x, t = threadIdx.x;
    if (bid < 4096) {
        int i = bid * 256 + t;
        float4 f = ((const float4*)x)[i];
        uint2 o;
        o.x = pk_bf16(f.x, f.y);
        o.y = pk_bf16(f.z, f.w);
        ((uint2*)x_bf)[i] = o;
        return;
    }
    const float* in; short* out; int C, r0, c0; float scale; int srows;
    if (bid < 7168) {
        int b2 = bid - 4096;              // 96 col-tiles x 32 row-tiles
        in = wqkv; out = wqkvT; C = QKVN;
        c0 = (b2 % 96) * 32; r0 = (b2 / 96) * 32;
        scale = smul; srows = 1024;       // scale Q columns (out rows < 1024)
    } else {
        int b3 = bid - 7168;              // 32 x 32
        in = wproj; out = wprojT; C = CDIM;
        c0 = (b3 & 31) * 32; r0 = (b3 >> 5) * 32;
        scale = 1.0f; srows = 0;
    }
    int tx = t & 31, ty = t >> 5;
    #pragma unroll
    for (int i = 0; i < 4; i++)
        tile[ty + i * 8][tx] = in[(size_t)(r0 + ty + i * 8) * C + c0 + tx];
    __syncthreads();
    #pragma unroll
    for (int i = 0; i < 4; i++) {
        int orow = c0 + ty + i * 8;
        float sc = (orow < srows) ? scale : 1.0f;
        out[(size_t)orow * CDIM + r0 + tx] = f2bf(tile[tx][ty + i * 8] * sc);
    }
}

// ---------------------------------------------------------------- GEMM core
// R1-validated structure (BK=64 staged as TWO 32-short panels, single-buffered,
// two barriers per K-step). R3's 2-phase dbuf REGRESSED (+12us): __syncthreads
// drains vmcnt(0) per step, so the 16-MFMA cluster had to cover full staging
// latency; counted-vmcnt (T4) is not expressible with __syncthreads.
template<int BF16OUT, int MT>
__device__ __forceinline__ void gemm_core(const short* __restrict__ A,
                                          const short* __restrict__ Bt,
                                          void* __restrict__ C,
                                          const float* __restrict__ bias,
                                          int N, int K, int m0, int n0,
                                          short* As, short* Bs) {
    constexpr int AF = MT / 32;
    constexpr int APAN = MT * 32;                  // A panel size (shorts)
    constexpr int BPAN = 128 * 32;
    const int t = threadIdx.x, wave = t >> 6, lane = t & 63;
    const int l15 = lane & 15, quad = lane >> 4;
    const int wr = wave >> 1, wc = wave & 1;
    const int sg = swz_src(lane);
    const int rsl = swz_rd(quad, l15);

    f32x4 acc[AF][4] = {};

    const short* gA = A  + (size_t)(m0 + wave * (MT / 4) + (lane >> 2)) * K + sg;
    const short* gB = Bt + (size_t)(n0 + wave * 32 + (lane >> 2)) * K + sg;
    short* lA = &As[wave * (MT / 4) * 32];
    short* lB = &Bs[wave * 32 * 32];

    for (int k0 = 0; k0 < K; k0 += 64) {
        // panel 0: k0..k0+31 ; panel 1: k0+32..k0+63
        glds16(gA + k0,      lA);
        glds16(gA + k0 + 32, lA + APAN);
        if constexpr (MT == 128) {
            glds16(gA + 16 * K + k0,      lA + 512);
            glds16(gA + 16 * K + k0 + 32, lA + APAN + 512);
        }
        glds16(gB + k0,               lB);
        glds16(gB + 16 * K + k0,      lB + 512);
        glds16(gB + k0 + 32,          lB + BPAN);
        glds16(gB + 16 * K + k0 + 32, lB + BPAN + 512);
        __syncthreads();

        #pragma unroll
        for (int st = 0; st < 2; st++) {
            bf16x8 af[AF], bfv[4];
            #pragma unroll
            for (int i = 0; i < AF; i++)
                af[i] = *(const bf16x8*)&As[st * APAN + (wr * (MT / 2) + i * 16 + l15) * 32 + rsl];
            #pragma unroll
            for (int j = 0; j < 4; j++)
                bfv[j] = *(const bf16x8*)&Bs[st * BPAN + (wc * 64 + j * 16 + l15) * 32 + rsl];
            #pragma unroll
            for (int i = 0; i < AF; i++)
                #pragma unroll
                for (int j = 0; j < 4; j++)
                    acc[i][j] = __builtin_amdgcn_mfma_f32_16x16x32_bf16(af[i], bfv[j], acc[i][j], 0, 0, 0);
        }
        __syncthreads();
    }

    #pragma unroll
    for (int i = 0; i < AF; i++) {
        #pragma unroll
        for (int j = 0; j < 4; j++) {
            #pragma unroll
            for (int r = 0; r < 4; r++) {
                int row = m0 + wr * (MT / 2) + i * 16 + quad * 4 + r;
                int col = n0 + wc * 64 + j * 16 + l15;
                float v = acc[i][j][r];
                if (BF16OUT) ((short*)C)[(size_t)row * N + col] = f2bf(v);
                else         ((float*)C)[(size_t)row * N + col] = v + bias[col];
            }
        }
    }
}

// fused QK-GEMM (blocks 0..511) + V^T-GEMM (blocks 512..767)
__global__ __launch_bounds__(256) void gemm_qk_v(const short* __restrict__ x_bf,
                                                 const short* __restrict__ wqkvT,
                                                 short* __restrict__ qk,
                                                 short* __restrict__ vT) {
    __shared__ __align__(16) short As[128 * 64];
    __shared__ __align__(16) short Bs[128 * 64];
    const int bid = blockIdx.x;
    if (bid < 512) {
        // QK = x @ Wqkv[:, :2048] : 32 m-tiles x 16 n-tiles
        gemm_core<1, 128>(x_bf, wqkvT, qk, nullptr, QKN, CDIM,
                          (bid >> 4) * 128, (bid & 15) * 128, As, Bs);
    } else {
        // V^T = Wv^T @ x^T : M=1024 (8 m-tiles of 128), N=4096 (32 n-tiles)
        int b2 = bid - 512;
        gemm_core<1, 128>(wqkvT + (size_t)QKN * CDIM, x_bf, vT, nullptr, ROWS, CDIM,
                          (b2 >> 5) * 128, (b2 & 31) * 128, As, Bs);
    }
}

// projection GEMM: out = attn @ Wproj + bias (f32 out). R1 config (MT=64).
__global__ __launch_bounds__(256) void gemm_proj(const short* __restrict__ A,
                                                 const short* __restrict__ Bt,
                                                 float* __restrict__ C,
                                                 const float* __restrict__ bias) {
    __shared__ __align__(16) short As[64 * 64];
    __shared__ __align__(16) short Bs[128 * 64];
    gemm_core<0, 64>(A, Bt, C, bias, CDIM, CDIM,
                     blockIdx.y * 64, blockIdx.x * 128, As, Bs);
}

// ---------------------------------------------------------------- flash attention
// R1: T2 chunk swizzle (conflicts 6.45M->164K), T5 setprio.
// R4: XCD work remap (FETCH 69.7->12.3 MB).
// R5: LDS 67.6->52KB (neutral: grid=512 caps at 2 blocks/CU — occupancy is
//     grid-limited, not LDS-limited).
// R6: ILP — software-pipeline the sub-loop one deep: QK-MFMA(sub+1) issued
//     BEFORE exp/PV of sub, with NO setprio fence between QK(sub+1) and
//     exp(sub) so the scheduler can dual-issue them to the MFMA and VALU
//     pipes (they're independent). Previously each wave was strictly serial
//     QK->exp->PV with setprio fences pinning the order (44%/44% pipes).
static constexpr int KBUF  = 2 * 128 * 32;        // one K double-panel buf = 8192 shorts
static constexpr int VOFF  = 2 * KBUF;            // 16384 shorts (after 2 K bufs)
static constexpr int LDV   = 136;                 // Vt ld (16B-aligned rows, bank-spread)
static constexpr int VBUF  = 64 * LDV;            // 8704 shorts (single buffer)
static constexpr int SMEM_SH = 26624;             // 53248 B

__global__ __launch_bounds__(512) void attn_kernel(const short* __restrict__ qk,
                                                   const short* __restrict__ vTg,
                                                   short* __restrict__ attn_out) {
    __shared__ __align__(16) short smem[SMEM_SH];

    const int t = threadIdx.x, wave = t >> 6, lane = t & 63;
    const int l15 = lane & 15, quad = lane >> 4;
    const int g = wave >> 2, wl = wave & 3;       // key-group, q-wave-local
    // XCD-aware remap (R4-verified): lid -> (bh, q0); XCD c = lid&7 owns bh in
    // {4c..4c+3} with all 16 q-tiles. Bijective: 512 = 8 XCD x 4 bh x 16 q.
    const int lid = blockIdx.x;
    const int bh = (lid & 7) * 4 + (lid >> 7);
    const int q0 = ((lid >> 3) & 15) * 128;
    const int b = bh >> 4, h = bh & 15;
    const size_t baseQ = (size_t)(b * SEQ) * QKN + h * 64;
    const int rsl = swz_rd(quad, l15);

    const size_t qoff0 = baseQ + (size_t)(q0 + wl * 32 + l15) * QKN + quad * 8;
    const size_t qoff1 = qoff0 + (size_t)16 * QKN;
    bf16x8 qf00 = *(const bf16x8*)&qk[qoff0];
    bf16x8 qf01 = *(const bf16x8*)&qk[qoff0 + 32];
    bf16x8 qf10 = *(const bf16x8*)&qk[qoff1];
    bf16x8 qf11 = *(const bf16x8*)&qk[qoff1 + 32];

    const short* gK = qk + baseQ + 1024
                    + (size_t)(wave * 16 + (lane >> 2)) * QKN + swz_src(lane);
    const short* gV = vTg + (size_t)(h * 64) * ROWS + b * SEQ;
    const int vd = t >> 3, vc = t & 7;

    const bf16x4 ones = { (short)0x3F80, (short)0x3F80, (short)0x3F80, (short)0x3F80 };

    f32x4 ot0[4] = {}, ot1[4] = {};
    f32x4 ol0 = {}, ol1 = {};

    short* Vbuf = smem + VOFF;

    // prologue: stage K[0] (async) and V[0] (reg->LDS), then one barrier
    glds16(gK,      smem + wave * 512);
    glds16(gK + 32, smem + 4096 + wave * 512);
    {
        int4 va = *(const int4*)&gV[(size_t)vd * ROWS + vc * 8];
        int4 vb = *(const int4*)&gV[(size_t)vd * ROWS + 64 + vc * 8];
        *(int4*)&Vbuf[vd * LDV + vc * 8]      = va;
        *(int4*)&Vbuf[vd * LDV + 64 + vc * 8] = vb;
    }
    __syncthreads();   // drains K[0] glds16 (vmcnt) + V[0] ds_writes (lgkmcnt)

    for (int j = 0; j < SEQ / 128; j++) {
        int4 va, vb;
        if (j < SEQ / 128 - 1) {
            const size_t jadd = (size_t)(j + 1) * 128 * QKN;
            short* kb = smem + ((j + 1) & 1) * KBUF + wave * 512;
            glds16(gK + jadd,      kb);                 // K dbuf: latency hidden
            glds16(gK + jadd + 32, kb + 4096);
            va = *(const int4*)&gV[(size_t)vd * ROWS + (j + 1) * 128 + vc * 8];
            vb = *(const int4*)&gV[(size_t)vd * ROWS + (j + 1) * 128 + 64 + vc * 8];
        }

        const short* Kb0 = smem + (j & 1) * KBUF;
        const short* Kb1 = Kb0 + 4096;

        // ---- sub pipeline: QK(0) prologue
        f32x4 a0c = {}, a1c = {};
        {
            const int gs0 = g * 4;
            bf16x8 kf0 = *(const bf16x8*)&Kb0[(gs0 * 16 + l15) * 32 + rsl];
            bf16x8 kf1 = *(const bf16x8*)&Kb1[(gs0 * 16 + l15) * 32 + rsl];
            __builtin_amdgcn_s_setprio(1);
            a0c = mfma32k_bf16(kf0, qf00, a0c);
            a0c = mfma32k_bf16(kf1, qf01, a0c);
            a1c = mfma32k_bf16(kf0, qf10, a1c);
            a1c = mfma32k_bf16(kf1, qf11, a1c);
            __builtin_amdgcn_s_setprio(0);
        }

        #pragma unroll
        for (int sub = 0; sub < 4; sub++) {
            const int gsub = g * 4 + sub;
            // QK(sub+1): independent of exp(sub) below — no fence between, so
            // the scheduler can issue these MFMAs under the exp2 VALU chain.
            f32x4 a0n = {}, a1n = {};
            if (sub < 3) {
                const int gs1 = gsub + 1;
                bf16x8 kf0n = *(const bf16x8*)&Kb0[(gs1 * 16 + l15) * 32 + rsl];
                bf16x8 kf1n = *(const bf16x8*)&Kb1[(gs1 * 16 + l15) * 32 + rsl];
                a0n = mfma32k_bf16(kf0n, qf00, a0n);
                a0n = mfma32k_bf16(kf1n, qf01, a0n);
                a1n = mfma32k_bf16(kf0n, qf10, a1n);
                a1n = mfma32k_bf16(kf1n, qf11, a1n);
            }
            // exp + pack of current sub
            union { unsigned u[2]; bf16x4 v; } pu0, pu1;
            pu0.u[0] = pk_bf16(__builtin_amdgcn_exp2f(a0c[0]), __builtin_amdgcn_exp2f(a0c[1]));
            pu0.u[1] = pk_bf16(__builtin_amdgcn_exp2f(a0c[2]), __builtin_amdgcn_exp2f(a0c[3]));
            pu1.u[0] = pk_bf16(__builtin_amdgcn_exp2f(a1c[0]), __builtin_amdgcn_exp2f(a1c[1]));
            pu1.u[1] = pk_bf16(__builtin_amdgcn_exp2f(a1c[2]), __builtin_amdgcn_exp2f(a1c[3]));
            // PV of current sub
            __builtin_amdgcn_s_setprio(1);
            ol0 = mfma16_bf16(ones, pu0.v, ol0);
            ol1 = mfma16_bf16(ones, pu1.v, ol1);
            #pragma unroll
            for (int d = 0; d < 4; d++) {
                bf16x4 vf = *(const bf16x4*)&Vbuf[(d * 16 + l15) * LDV + gsub * 16 + quad * 4];
                ot0[d] = mfma16_bf16(vf, pu0.v, ot0[d]);
                ot1[d] = mfma16_bf16(vf, pu1.v, ot1[d]);
            }
            __builtin_amdgcn_s_setprio(0);
            a0c = a0n; a1c = a1n;
        }

        // barrier B: all waves done reading Vbuf (and K[j]); drains vmcnt so
        // K[j+1] glds16 + V[j+1] global loads have landed.
        __syncthreads();
        if (j < SEQ / 128 - 1) {
            *(int4*)&Vbuf[vd * LDV + vc * 8]      = va;
            *(int4*)&Vbuf[vd * LDV + 64 + vc * 8] = vb;
            // barrier A: V[j+1] writes visible before next iteration's reads
            __syncthreads();
        }
    }

    // ---- epilogue: cross-group reduction + normalize + transpose + store
    __syncthreads();
    float* pf = (float*)smem;                   // [128 q][68] f32; col 64 = l
    short* tr = smem + 17408;                   // byte 34816: [128 q][72] bf16

    if (g == 1) {
        #pragma unroll
        for (int d = 0; d < 4; d++) {
            #pragma unroll
            for (int r = 0; r < 4; r++) {
                pf[(wl * 32 + l15) * 68      + d * 16 + quad * 4 + r] = ot0[d][r];
                pf[(wl * 32 + 16 + l15) * 68 + d * 16 + quad * 4 + r] = ot1[d][r];
            }
        }
        pf[(wl * 32 + l15) * 68 + 64]      = ol0[0];
        pf[(wl * 32 + 16 + l15) * 68 + 64] = ol1[0];
    }
    __syncthreads();
    if (g == 0) {
        float inv0 = 1.0f / (ol0[0] + pf[(wl * 32 + l15) * 68 + 64]);
        float inv1 = 1.0f / (ol1[0] + pf[(wl * 32 + 16 + l15) * 68 + 64]);
        #pragma unroll
        for (int d = 0; d < 4; d++) {
            int pb0 = (wl * 32 + l15) * 68      + d * 16 + quad * 4;
            int pb1 = (wl * 32 + 16 + l15) * 68 + d * 16 + quad * 4;
            float c00 = (ot0[d][0] + pf[pb0 + 0]) * inv0;
            float c01 = (ot0[d][1] + pf[pb0 + 1]) * inv0;
            float c02 = (ot0[d][2] + pf[pb0 + 2]) * inv0;
            float c03 = (ot0[d][3] + pf[pb0 + 3]) * inv0;
            float c10 = (ot1[d][0] + pf[pb1 + 0]) * inv1;
            float c11 = (ot1[d][1] + pf[pb1 + 1]) * inv1;
            float c12 = (ot1[d][2] + pf[pb1 + 2]) * inv1;
            float c13 = (ot1[d][3] + pf[pb1 + 3]) * inv1;
            int o0 = (wl * 32 + l15) * 72 + d * 16 + quad * 4;
            int o1 = (wl * 32 + 16 + l15) * 72 + d * 16 + quad * 4;
            *(unsigned*)&tr[o0]     = pk_bf16(c00, c01);
            *(unsigned*)&tr[o0 + 2] = pk_bf16(c02, c03);
            *(unsigned*)&tr[o1]     = pk_bf16(c10, c11);
            *(unsigned*)&tr[o1 + 2] = pk_bf16(c12, c13);
        }
    }
    __syncthreads();
    {
        // coverage: 512 thr x 2 int4 = 1024 = 128 rows x 8 chunks ✓
        int row = t >> 2, c4 = t & 3;
        #pragma unroll
        for (int p = 0; p < 2; p++) {
            int ch = c4 * 2 + p;
            int4 v = *(const int4*)&tr[row * 72 + ch * 8];
            *(int4*)&attn_out[(size_t)(b * SEQ + q0 + row) * CDIM + h * 64 + ch * 8] = v;
        }
    }
}

// ---------------------------------------------------------------- launch
extern "C" void kernel_launch(void* const* d_in, const int* in_sizes, int n_in,
                              void* d_out, int out_size, void* d_ws, size_t ws_size,
                              hipStream_t stream) {
    const float* x      = (const float*)d_in[0];
    const float* w_qkv  = (const float*)d_in[1];
    const float* w_proj = (const float*)d_in[2];
    const float* b_proj = (const float*)d_in[3];
    float* out = (float*)d_out;

    char* ws = (char*)d_ws;
    short* x_bf    = (short*)(ws);                 //  8 MB  [4096][1024]
    short* wqkvT   = (short*)(ws + 8388608);       //  6 MB  [3072][1024]
    short* wprojT  = (short*)(ws + 14680064);      //  2 MB  [1024][1024]
    short* qk_bf   = (short*)(ws + 16777216);      // 16 MB  [4096][2048]
    short* vTg     = (short*)(ws + 33554432);      //  8 MB  [1024][4096]
    short* attn_bf = (short*)(ws + 41943040);      //  8 MB  [4096][1024]

    const float SMUL = 0.125f * 1.44269504088896340736f;  // scale * log2(e)

    prep<<<8192, 256, 0, stream>>>(x, w_qkv, w_proj, x_bf, wqkvT, wprojT, SMUL);

    gemm_qk_v<<<768, 256, 0, stream>>>(x_bf, wqkvT, qk_bf, vTg);

    attn_kernel<<<dim3(512), 512, 0, stream>>>(qk_bf, vTg, attn_bf);

    gemm_proj<<<dim3(CDIM / 128, ROWS / 64), 256, 0, stream>>>(attn_bf, wprojT, out, b_proj);
}

// Round 7
// 180.612 us; speedup vs baseline: 1.0308x; 1.0308x over previous
//
#include <hip/hip_runtime.h>
#include <hip/hip_bf16.h>
#include <cstdint>
#include <cstddef>

// B=2, N=2048, C=1024, HEADS=16, DIM_HEAD=64
static constexpr int BATCH = 2;
static constexpr int SEQ   = 2048;
static constexpr int CDIM  = 1024;
static constexpr int ROWS  = BATCH * SEQ;   // 4096
static constexpr int QKVN  = 3 * CDIM;      // 3072
static constexpr int QKN   = 2 * CDIM;      // 2048 (Q,K only)

typedef short bf16x8 __attribute__((ext_vector_type(8)));
typedef short bf16x4 __attribute__((ext_vector_type(4)));
typedef float f32x4  __attribute__((ext_vector_type(4)));

__device__ inline short f2bf(float f) {
    union { float f; unsigned u; } v; v.f = f;
    unsigned u = v.u;
    u += 0x7fffu + ((u >> 16) & 1u);
    return (short)(u >> 16);
}

// pack two f32 -> two bf16 (RNE) in one dword; a -> low16, b -> high16
__device__ inline unsigned pk_bf16(float a, float b) {
#if __has_builtin(__builtin_amdgcn_cvt_pk_bf16_f32)
    auto r = __builtin_amdgcn_cvt_pk_bf16_f32(a, b);   // v_cvt_pk_bf16_f32 (gfx950)
    return __builtin_bit_cast(unsigned, r);
#else
    union { float f; unsigned u; } ua, ub;
    ua.f = a; ub.f = b;
    unsigned xa = ua.u + 0x7fffu + ((ua.u >> 16) & 1u);
    unsigned xb = ub.u + 0x7fffu + ((ub.u >> 16) & 1u);
    return __builtin_amdgcn_perm(xb, xa, 0x07060302);
#endif
}

// async global->LDS, 16B/lane; LDS dest = wave-uniform base + lane*16 (m104)
__device__ inline void glds16(const short* g, short* l) {
    __builtin_amdgcn_global_load_lds(
        (const __attribute__((address_space(1))) void*)g,
        (__attribute__((address_space(3))) void*)l, 16, 0, 0);
}

__device__ inline f32x4 mfma16_bf16(bf16x4 a, bf16x4 b, f32x4 c) {
#if __has_builtin(__builtin_amdgcn_mfma_f32_16x16x16bf16_1k)
    return __builtin_amdgcn_mfma_f32_16x16x16bf16_1k(a, b, c, 0, 0, 0);
#else
    asm("v_mfma_f32_16x16x16_bf16 %0, %1, %2, %0" : "+v"(c) : "v"(a), "v"(b));
    return c;
#endif
}

// ---- LDS chunk swizzle (T2, both-sides per rule 21) ------------------------
// Panels are 16-row x 32-short (64B rows), staged by glds16 with linear LDS
// dest (lane*16B). Un-swizzled, all 16 lanes of a quad-group read the SAME
// 16B column slot of rows 64B apart -> 8-way bank conflict. Fix: XOR the
// chunk index with (row>>1)&3 on BOTH the global source (staging) and the
// LDS read slot. (R1-verified: attn SQ_LDS_BANK_CONFLICT 6.45M -> 164K.)
__device__ inline int swz_src(int lane) {            // staging: global chunk, in shorts
    return ((lane & 3) ^ ((lane >> 3) & 3)) * 8;     // (row_local>>1)&3 == (lane>>3)&3
}
__device__ inline int swz_rd(int quad, int l15) {    // read slot, in shorts
    return (quad ^ ((l15 >> 1) & 3)) * 8;            // (panel_row>>1)&3 == (l15>>1)&3
}

// ---------------------------------------------------------------- fused prep
__global__ __launch_bounds__(256) void prep(const float* __restrict__ x,
                                            const float* __restrict__ wqkv,
                                            const float* __restrict__ wproj,
                                            short* __restrict__ x_bf,
                                            short* __restrict__ wqkvT,
                                            short* __restrict__ wprojT,
                                            float smul) {
    __shared__ float tile[32][33];
    const int bid = blockIdx.x, t = threadIdx.x;
    if (bid < 4096) {
        int i = bid * 256 + t;
        float4 f = ((const float4*)x)[i];
        uint2 o;
        o.x = pk_bf16(f.x, f.y);
        o.y = pk_bf16(f.z, f.w);
        ((uint2*)x_bf)[i] = o;
        return;
    }
    const float* in; short* out; int C, r0, c0; float scale; int srows;
    if (bid < 7168) {
        int b2 = bid - 4096;              // 96 col-tiles x 32 row-tiles
        in = wqkv; out = wqkvT; C = QKVN;
        c0 = (b2 % 96) * 32; r0 = (b2 / 96) * 32;
        scale = smul; srows = 1024;       // scale Q columns (out rows < 1024)
    } else {
        int b3 = bid - 7168;              // 32 x 32
        in = wproj; out = wprojT; C = CDIM;
        c0 = (b3 & 31) * 32; r0 = (b3 >> 5) * 32;
        scale = 1.0f; srows = 0;
    }
    int tx = t & 31, ty = t >> 5;
    #pragma unroll
    for (int i = 0; i < 4; i++)
        tile[ty + i * 8][tx] = in[(size_t)(r0 + ty + i * 8) * C + c0 + tx];
    __syncthreads();
    #pragma unroll
    for (int i = 0; i < 4; i++) {
        int orow = c0 + ty + i * 8;
        float sc = (orow < srows) ? scale : 1.0f;
        out[(size_t)orow * CDIM + r0 + tx] = f2bf(tile[tx][ty + i * 8] * sc);
    }
}

// ---------------------------------------------------------------- GEMM core
// R1-validated structure (BK=64 staged as TWO 32-short panels, single-buffered,
// two barriers per K-step). R3's 2-phase dbuf REGRESSED (+12us): __syncthreads
// drains vmcnt(0) per step, so the 16-MFMA cluster had to cover full staging
// latency; counted-vmcnt (T4) is not expressible with __syncthreads.
template<int BF16OUT, int MT>
__device__ __forceinline__ void gemm_core(const short* __restrict__ A,
                                          const short* __restrict__ Bt,
                                          void* __restrict__ C,
                                          const float* __restrict__ bias,
                                          int N, int K, int m0, int n0,
                                          short* As, short* Bs) {
    constexpr int AF = MT / 32;
    constexpr int APAN = MT * 32;                  // A panel size (shorts)
    constexpr int BPAN = 128 * 32;
    const int t = threadIdx.x, wave = t >> 6, lane = t & 63;
    const int l15 = lane & 15, quad = lane >> 4;
    const int wr = wave >> 1, wc = wave & 1;
    const int sg = swz_src(lane);
    const int rsl = swz_rd(quad, l15);

    f32x4 acc[AF][4] = {};

    const short* gA = A  + (size_t)(m0 + wave * (MT / 4) + (lane >> 2)) * K + sg;
    const short* gB = Bt + (size_t)(n0 + wave * 32 + (lane >> 2)) * K + sg;
    short* lA = &As[wave * (MT / 4) * 32];
    short* lB = &Bs[wave * 32 * 32];

    for (int k0 = 0; k0 < K; k0 += 64) {
        // panel 0: k0..k0+31 ; panel 1: k0+32..k0+63
        glds16(gA + k0,      lA);
        glds16(gA + k0 + 32, lA + APAN);
        if constexpr (MT == 128) {
            glds16(gA + 16 * K + k0,      lA + 512);
            glds16(gA + 16 * K + k0 + 32, lA + APAN + 512);
        }
        glds16(gB + k0,               lB);
        glds16(gB + 16 * K + k0,      lB + 512);
        glds16(gB + k0 + 32,          lB + BPAN);
        glds16(gB + 16 * K + k0 + 32, lB + BPAN + 512);
        __syncthreads();

        #pragma unroll
        for (int st = 0; st < 2; st++) {
            bf16x8 af[AF], bfv[4];
            #pragma unroll
            for (int i = 0; i < AF; i++)
                af[i] = *(const bf16x8*)&As[st * APAN + (wr * (MT / 2) + i * 16 + l15) * 32 + rsl];
            #pragma unroll
            for (int j = 0; j < 4; j++)
                bfv[j] = *(const bf16x8*)&Bs[st * BPAN + (wc * 64 + j * 16 + l15) * 32 + rsl];
            #pragma unroll
            for (int i = 0; i < AF; i++)
                #pragma unroll
                for (int j = 0; j < 4; j++)
                    acc[i][j] = __builtin_amdgcn_mfma_f32_16x16x32_bf16(af[i], bfv[j], acc[i][j], 0, 0, 0);
        }
        __syncthreads();
    }

    #pragma unroll
    for (int i = 0; i < AF; i++) {
        #pragma unroll
        for (int j = 0; j < 4; j++) {
            #pragma unroll
            for (int r = 0; r < 4; r++) {
                int row = m0 + wr * (MT / 2) + i * 16 + quad * 4 + r;
                int col = n0 + wc * 64 + j * 16 + l15;
                float v = acc[i][j][r];
                if (BF16OUT) ((short*)C)[(size_t)row * N + col] = f2bf(v);
                else         ((float*)C)[(size_t)row * N + col] = v + bias[col];
            }
        }
    }
}

// fused QK-GEMM (blocks 0..511) + V^T-GEMM (blocks 512..767)
// R7: XCD-aware 2D chunking (T1). Old linear map put XCD c on n-tiles {c,c+8}
// for EVERY m -> each XCD streamed the whole 8MB A through its 4MB L2
// (FETCH 45MB vs 14MB ideal, R0 counters). New map: XCD c = bid&7 owns a
// contiguous m x n chunk whose A-panel + B-panel fit L2:
//   QK:  8m x 8n tiles -> 2MB A + 2MB B = 4MB.
//   V^T: 4m x 8n tiles -> 1MB A + 2MB B = 3MB.
// Bijective: (c&3,mi) and (c>>2,ni) partition the tile space exactly.
__global__ __launch_bounds__(256) void gemm_qk_v(const short* __restrict__ x_bf,
                                                 const short* __restrict__ wqkvT,
                                                 short* __restrict__ qk,
                                                 short* __restrict__ vT) {
    __shared__ __align__(16) short As[128 * 64];
    __shared__ __align__(16) short Bs[128 * 64];
    const int bid = blockIdx.x;
    if (bid < 512) {
        // QK = x @ Wqkv[:, :2048] : 32 m-tiles x 16 n-tiles
        const int c = bid & 7, i = bid >> 3;       // c = XCD, i in 0..63
        const int mi = i & 7, ni = i >> 3;         // 8x8 chunk
        const int m0 = ((c & 3) * 8 + mi) * 128;   // 4 m-chunks of 8
        const int n0 = ((c >> 2) * 8 + ni) * 128;  // 2 n-chunks of 8
        gemm_core<1, 128>(x_bf, wqkvT, qk, nullptr, QKN, CDIM, m0, n0, As, Bs);
    } else {
        // V^T = Wv^T @ x^T : M=1024 (8 m-tiles), N=4096 (32 n-tiles)
        const int b2 = bid - 512;                  // 512%8==0 -> XCD = b2&7
        const int c = b2 & 7, i = b2 >> 3;         // i in 0..31
        const int mi = i & 3, ni = i >> 2;         // 4x8 chunk
        const int m0 = ((c & 1) * 4 + mi) * 128;   // 2 m-chunks of 4
        const int n0 = ((c >> 1) * 8 + ni) * 128;  // 4 n-chunks of 8
        gemm_core<1, 128>(wqkvT + (size_t)QKN * CDIM, x_bf, vT, nullptr, ROWS, CDIM,
                          m0, n0, As, Bs);
    }
}

// projection GEMM: out = attn @ Wproj + bias (f32 out). R7: 1-D grid of 512
// with XCD chunking — old (8,64) grid gave XCD c = bx&7 one n-column for all
// 64 m-tiles -> every XCD streamed the whole 8MB A. New: XCD c owns m-tiles
// c*8..c*8+7 x all 8 n -> 1MB A + 2MB B per XCD.
__global__ __launch_bounds__(256) void gemm_proj(const short* __restrict__ A,
                                                 const short* __restrict__ Bt,
                                                 float* __restrict__ C,
                                                 const float* __restrict__ bias) {
    __shared__ __align__(16) short As[64 * 64];
    __shared__ __align__(16) short Bs[128 * 64];
    const int bid = blockIdx.x;
    const int c = bid & 7, i = bid >> 3;           // i in 0..63
    const int mi = i & 7, ni = i >> 3;             // 8 m x 8 n chunk
    const int m0 = (c * 8 + mi) * 64;              // 64 m-tiles of 64 rows
    const int n0 = ni * 128;                       // 8 n-tiles
    gemm_core<0, 64>(A, Bt, C, bias, CDIM, CDIM, m0, n0, As, Bs);
}

// ---------------------------------------------------------------- flash attention
// R1: T2 chunk swizzle (conflicts 6.45M->164K), T5 setprio.
// R4: XCD work remap (FETCH 69.7->12.3 MB).
// R5: LDS 67.6->52KB, V single-buffered (attn best: 53.1 us).
// R6 sub-skew REVERTED: +3.2us, VGPR 48->56, no pipe-util change — compiler
// already schedules across the chain; the skew only added copies/pressure.
static constexpr int KBUF  = 2 * 128 * 32;        // one K double-panel buf = 8192 shorts
static constexpr int VOFF  = 2 * KBUF;            // 16384 shorts (after 2 K bufs)
static constexpr int LDV   = 136;                 // Vt ld (16B-aligned rows, bank-spread)
static constexpr int VBUF  = 64 * LDV;            // 8704 shorts (single buffer)
static constexpr int SMEM_SH = 26624;             // 53248 B

__global__ __launch_bounds__(512) void attn_kernel(const short* __restrict__ qk,
                                                   const short* __restrict__ vTg,
                                                   short* __restrict__ attn_out) {
    __shared__ __align__(16) short smem[SMEM_SH];

    const int t = threadIdx.x, wave = t >> 6, lane = t & 63;
    const int l15 = lane & 15, quad = lane >> 4;
    const int g = wave >> 2, wl = wave & 3;       // key-group, q-wave-local
    // XCD-aware remap (R4-verified): lid -> (bh, q0); XCD c = lid&7 owns bh in
    // {4c..4c+3} with all 16 q-tiles. Bijective: 512 = 8 XCD x 4 bh x 16 q.
    const int lid = blockIdx.x;
    const int bh = (lid & 7) * 4 + (lid >> 7);
    const int q0 = ((lid >> 3) & 15) * 128;
    const int b = bh >> 4, h = bh & 15;
    const size_t baseQ = (size_t)(b * SEQ) * QKN + h * 64;
    const int rsl = swz_rd(quad, l15);

    const size_t qoff0 = baseQ + (size_t)(q0 + wl * 32 + l15) * QKN + quad * 8;
    const size_t qoff1 = qoff0 + (size_t)16 * QKN;
    bf16x8 qf00 = *(const bf16x8*)&qk[qoff0];
    bf16x8 qf01 = *(const bf16x8*)&qk[qoff0 + 32];
    bf16x8 qf10 = *(const bf16x8*)&qk[qoff1];
    bf16x8 qf11 = *(const bf16x8*)&qk[qoff1 + 32];

    const short* gK = qk + baseQ + 1024
                    + (size_t)(wave * 16 + (lane >> 2)) * QKN + swz_src(lane);
    const short* gV = vTg + (size_t)(h * 64) * ROWS + b * SEQ;
    const int vd = t >> 3, vc = t & 7;

    const bf16x4 ones = { (short)0x3F80, (short)0x3F80, (short)0x3F80, (short)0x3F80 };

    f32x4 ot0[4] = {}, ot1[4] = {};
    f32x4 ol0 = {}, ol1 = {};

    short* Vbuf = smem + VOFF;

    // prologue: stage K[0] (async) and V[0] (reg->LDS), then one barrier
    glds16(gK,      smem + wave * 512);
    glds16(gK + 32, smem + 4096 + wave * 512);
    {
        int4 va = *(const int4*)&gV[(size_t)vd * ROWS + vc * 8];
        int4 vb = *(const int4*)&gV[(size_t)vd * ROWS + 64 + vc * 8];
        *(int4*)&Vbuf[vd * LDV + vc * 8]      = va;
        *(int4*)&Vbuf[vd * LDV + 64 + vc * 8] = vb;
    }
    __syncthreads();   // drains K[0] glds16 (vmcnt) + V[0] ds_writes (lgkmcnt)

    for (int j = 0; j < SEQ / 128; j++) {
        int4 va, vb;
        if (j < SEQ / 128 - 1) {
            const size_t jadd = (size_t)(j + 1) * 128 * QKN;
            short* kb = smem + ((j + 1) & 1) * KBUF + wave * 512;
            glds16(gK + jadd,      kb);                 // K dbuf: latency hidden
            glds16(gK + jadd + 32, kb + 4096);
            va = *(const int4*)&gV[(size_t)vd * ROWS + (j + 1) * 128 + vc * 8];
            vb = *(const int4*)&gV[(size_t)vd * ROWS + (j + 1) * 128 + 64 + vc * 8];
        }

        const short* Kb0 = smem + (j & 1) * KBUF;
        const short* Kb1 = Kb0 + 4096;

        #pragma unroll
        for (int sub = 0; sub < 4; sub++) {
            const int gsub = g * 4 + sub;
            bf16x8 kf0 = *(const bf16x8*)&Kb0[(gsub * 16 + l15) * 32 + rsl];
            bf16x8 kf1 = *(const bf16x8*)&Kb1[(gsub * 16 + l15) * 32 + rsl];
            f32x4 a0 = {}, a1 = {};
            __builtin_amdgcn_s_setprio(1);
            a0 = __builtin_amdgcn_mfma_f32_16x16x32_bf16(kf0, qf00, a0, 0, 0, 0);
            a0 = __builtin_amdgcn_mfma_f32_16x16x32_bf16(kf1, qf01, a0, 0, 0, 0);
            a1 = __builtin_amdgcn_mfma_f32_16x16x32_bf16(kf0, qf10, a1, 0, 0, 0);
            a1 = __builtin_amdgcn_mfma_f32_16x16x32_bf16(kf1, qf11, a1, 0, 0, 0);
            __builtin_amdgcn_s_setprio(0);
            union { unsigned u[2]; bf16x4 v; } pu0, pu1;
            pu0.u[0] = pk_bf16(__builtin_amdgcn_exp2f(a0[0]), __builtin_amdgcn_exp2f(a0[1]));
            pu0.u[1] = pk_bf16(__builtin_amdgcn_exp2f(a0[2]), __builtin_amdgcn_exp2f(a0[3]));
            pu1.u[0] = pk_bf16(__builtin_amdgcn_exp2f(a1[0]), __builtin_amdgcn_exp2f(a1[1]));
            pu1.u[1] = pk_bf16(__builtin_amdgcn_exp2f(a1[2]), __builtin_amdgcn_exp2f(a1[3]));
            __builtin_amdgcn_s_setprio(1);
            ol0 = mfma16_bf16(ones, pu0.v, ol0);
            ol1 = mfma16_bf16(ones, pu1.v, ol1);
            #pragma unroll
            for (int d = 0; d < 4; d++) {
                bf16x4 vf = *(const bf16x4*)&Vbuf[(d * 16 + l15) * LDV + gsub * 16 + quad * 4];
                ot0[d] = mfma16_bf16(vf, pu0.v, ot0[d]);
                ot1[d] = mfma16_bf16(vf, pu1.v, ot1[d]);
            }
            __builtin_amdgcn_s_setprio(0);
        }

        // barrier B: all waves done reading Vbuf (and K[j]); drains vmcnt so
        // K[j+1] glds16 + V[j+1] global loads have landed.
        __syncthreads();
        if (j < SEQ / 128 - 1) {
            *(int4*)&Vbuf[vd * LDV + vc * 8]      = va;
            *(int4*)&Vbuf[vd * LDV + 64 + vc * 8] = vb;
            // barrier A: V[j+1] writes visible before next iteration's reads
            __syncthreads();
        }
    }

    // ---- epilogue: cross-group reduction + normalize + transpose + store
    __syncthreads();
    float* pf = (float*)smem;                   // [128 q][68] f32; col 64 = l
    short* tr = smem + 17408;                   // byte 34816: [128 q][72] bf16

    if (g == 1) {
        #pragma unroll
        for (int d = 0; d < 4; d++) {
            #pragma unroll
            for (int r = 0; r < 4; r++) {
                pf[(wl * 32 + l15) * 68      + d * 16 + quad * 4 + r] = ot0[d][r];
                pf[(wl * 32 + 16 + l15) * 68 + d * 16 + quad * 4 + r] = ot1[d][r];
            }
        }
        pf[(wl * 32 + l15) * 68 + 64]      = ol0[0];
        pf[(wl * 32 + 16 + l15) * 68 + 64] = ol1[0];
    }
    __syncthreads();
    if (g == 0) {
        float inv0 = 1.0f / (ol0[0] + pf[(wl * 32 + l15) * 68 + 64]);
        float inv1 = 1.0f / (ol1[0] + pf[(wl * 32 + 16 + l15) * 68 + 64]);
        #pragma unroll
        for (int d = 0; d < 4; d++) {
            int pb0 = (wl * 32 + l15) * 68      + d * 16 + quad * 4;
            int pb1 = (wl * 32 + 16 + l15) * 68 + d * 16 + quad * 4;
            float c00 = (ot0[d][0] + pf[pb0 + 0]) * inv0;
            float c01 = (ot0[d][1] + pf[pb0 + 1]) * inv0;
            float c02 = (ot0[d][2] + pf[pb0 + 2]) * inv0;
            float c03 = (ot0[d][3] + pf[pb0 + 3]) * inv0;
            float c10 = (ot1[d][0] + pf[pb1 + 0]) * inv1;
            float c11 = (ot1[d][1] + pf[pb1 + 1]) * inv1;
            float c12 = (ot1[d][2] + pf[pb1 + 2]) * inv1;
            float c13 = (ot1[d][3] + pf[pb1 + 3]) * inv1;
            int o0 = (wl * 32 + l15) * 72 + d * 16 + quad * 4;
            int o1 = (wl * 32 + 16 + l15) * 72 + d * 16 + quad * 4;
            *(unsigned*)&tr[o0]     = pk_bf16(c00, c01);
            *(unsigned*)&tr[o0 + 2] = pk_bf16(c02, c03);
            *(unsigned*)&tr[o1]     = pk_bf16(c10, c11);
            *(unsigned*)&tr[o1 + 2] = pk_bf16(c12, c13);
        }
    }
    __syncthreads();
    {
        // coverage: 512 thr x 2 int4 = 1024 = 128 rows x 8 chunks ✓
        int row = t >> 2, c4 = t & 3;
        #pragma unroll
        for (int p = 0; p < 2; p++) {
            int ch = c4 * 2 + p;
            int4 v = *(const int4*)&tr[row * 72 + ch * 8];
            *(int4*)&attn_out[(size_t)(b * SEQ + q0 + row) * CDIM + h * 64 + ch * 8] = v;
        }
    }
}

// ---------------------------------------------------------------- launch
extern "C" void kernel_launch(void* const* d_in, const int* in_sizes, int n_in,
                              void* d_out, int out_size, void* d_ws, size_t ws_size,
                              hipStream_t stream) {
    const float* x      = (const float*)d_in[0];
    const float* w_qkv  = (const float*)d_in[1];
    const float* w_proj = (const float*)d_in[2];
    const float* b_proj = (const float*)d_in[3];
    float* out = (float*)d_out;

    char* ws = (char*)d_ws;
    short* x_bf    = (short*)(ws);                 //  8 MB  [4096][1024]
    short* wqkvT   = (short*)(ws + 8388608);       //  6 MB  [3072][1024]
    short* wprojT  = (short*)(ws + 14680064);      //  2 MB  [1024][1024]
    short* qk_bf   = (short*)(ws + 16777216);      // 16 MB  [4096][2048]
    short* vTg     = (short*)(ws + 33554432);      //  8 MB  [1024][4096]
    short* attn_bf = (short*)(ws + 41943040);      //  8 MB  [4096][1024]

    const float SMUL = 0.125f * 1.44269504088896340736f;  // scale * log2(e)

    prep<<<8192, 256, 0, stream>>>(x, w_qkv, w_proj, x_bf, wqkvT, wprojT, SMUL);

    gemm_qk_v<<<768, 256, 0, stream>>>(x_bf, wqkvT, qk_bf, vTg);

    attn_kernel<<<dim3(512), 512, 0, stream>>>(qk_bf, vTg, attn_bf);

    gemm_proj<<<512, 256, 0, stream>>>(attn_bf, wprojT, out, b_proj);
}